// Round 4
// baseline (3337.616 us; speedup 1.0000x reference)
//
#include <hip/hip_runtime.h>
#include <hip/hip_bf16.h>

#define BB 256   // batch
#define TT 512   // time
#define HH 256   // hidden
#define EE 128   // embed
#define KK 15    // tags
#define NGRP 16  // batch groups per direction
#define GB   16  // batch rows per group

typedef __attribute__((ext_vector_type(8))) short short8;
typedef __attribute__((ext_vector_type(4))) float floatx4;

__device__ __forceinline__ float fsig(float x) { return 1.0f / (1.0f + __expf(-x)); }
__device__ __forceinline__ float ftanh(float x) {
    float e = __expf(2.0f * x);
    return 1.0f - 2.0f / (e + 1.0f);
}
__device__ __forceinline__ unsigned short f2b(float f) {
    __hip_bfloat16 h = __float2bfloat16(f);
    return *reinterpret_cast<unsigned short*>(&h);
}
__device__ __forceinline__ float b2f(unsigned short u) {
    unsigned v = ((unsigned)u) << 16;
    return *reinterpret_cast<float*>(&v);
}

// ---------------- prep: transpose ids/labels to [T][B] ----------------
__global__ void prep_transpose(const int* __restrict__ cids, const int* __restrict__ labels,
                               int* __restrict__ cidsT, int* __restrict__ labelsT) {
    int idx = blockIdx.x * 256 + threadIdx.x;
    int which = idx >> 17;
    int r = idx & 131071;
    int b = r >> 9, t = r & 511;
    if (which == 0) cidsT[t * BB + b] = cids[b * TT + t];
    else            labelsT[t * BB + b] = labels[b * TT + t];
}

// ---------------- tables (bf16): table[d][v][j] = b_d[j] + embed[v] . Wih_d[j] ----------------
__global__ void build_tables(const float* __restrict__ embed,
                             const float* __restrict__ WihF, const float* __restrict__ bF,
                             const float* __restrict__ WihB, const float* __restrict__ bB,
                             unsigned short* __restrict__ tableF, unsigned short* __restrict__ tableB) {
    int idx = blockIdx.x * 256 + threadIdx.x;
    int d = idx >> 17;
    int r = idx & 131071;
    int v = r >> 10, j = r & 1023;
    const float* Wih = d ? WihB : WihF;
    const float* bias = d ? bB : bF;
    float s = bias[j];
    const float* em = embed + v * EE;
    const float* wr = Wih + j * EE;
#pragma unroll 8
    for (int e = 0; e < EE; ++e) s += em[e] * wr[e];
    (d ? tableB : tableF)[v * 1024 + j] = f2b(s);
}

// ---------------- BiLSTM: one block per (dir, group) — no inter-block sync ----------------
// 32 blocks x 512 threads (8 waves, 2 waves/SIMD, VGPR cap 256).
// Wave wv owns h-cols [wv*32, wv*32+32) x 4 gates = 8 A-tiles (16 gate-rows x K).
// Tiles q=0..2 (i,f,g) register-resident (192 VGPR); q=3 (o) streamed from LDS.
// MFMA: A = W-tile (M=gate-rows), B = h (N=batch). B-frag shared by all tiles.
// h exchanged via LDS in B-fragment-linear layout, double-buffered; 1 barrier/step.
__global__ void __launch_bounds__(512, 2)
bilstm(const unsigned short* __restrict__ tableF, const unsigned short* __restrict__ tableB,
       const float* __restrict__ WhhF, const float* __restrict__ WhhB,
       const float* __restrict__ fcW,
       const int* __restrict__ cidsT,
       float* __restrict__ emF, float* __restrict__ emB) {
    const int bid = blockIdx.x;
    const int dir = bid >> 4;
    const int g   = bid & 15;
    const int tid = threadIdx.x;
    const int wv   = tid >> 6;       // 0..7
    const int lane = tid & 63;
    const int lo   = lane & 15;
    const int hi   = lane >> 4;      // 0..3

    const unsigned short* table = dir ? tableB : tableF;
    const float* Whh   = dir ? WhhB : WhhF;
    float* emOut       = dir ? emB : emF;

    __shared__ __align__(16) unsigned short wlds[16 * 8 * 512];  // 128 KiB: [(wv*2+t2)*8+kb][lane*8]
    __shared__ __align__(16) unsigned short fclds[8 * 512];      // 8 KiB:  [kb][lane*8]
    __shared__ __align__(16) unsigned short hfr[2 * 8 * 512];    // 16 KiB: [buf][kb][lane*8]

    // ---- preload register-resident W tiles (q=0..2) ----
    short8 wfrag[6][8];
#pragma unroll
    for (int tl = 0; tl < 6; ++tl) {
        const int q = tl >> 1, ct = tl & 1;
        const float* wr = Whh + (size_t)(q * HH + wv * 32 + ct * 16 + lo) * HH;
#pragma unroll
        for (int kb = 0; kb < 8; ++kb) {
            const float4* p4 = (const float4*)(wr + kb * 32 + hi * 8);
            float4 a = p4[0], b = p4[1];
            short8 f;
            f[0] = (short)f2b(a.x); f[1] = (short)f2b(a.y);
            f[2] = (short)f2b(a.z); f[3] = (short)f2b(a.w);
            f[4] = (short)f2b(b.x); f[5] = (short)f2b(b.y);
            f[6] = (short)f2b(b.z); f[7] = (short)f2b(b.w);
            wfrag[tl][kb] = f;
        }
    }
    // ---- o-gate tiles (q=3) -> LDS, fragment-linear ----
#pragma unroll
    for (int t2 = 0; t2 < 2; ++t2) {
        const float* wr = Whh + (size_t)(3 * HH + wv * 32 + t2 * 16 + lo) * HH;
#pragma unroll
        for (int kb = 0; kb < 8; ++kb) {
            const float4* p4 = (const float4*)(wr + kb * 32 + hi * 8);
            float4 a = p4[0], b = p4[1];
            short8 f;
            f[0] = (short)f2b(a.x); f[1] = (short)f2b(a.y);
            f[2] = (short)f2b(a.z); f[3] = (short)f2b(a.w);
            f[4] = (short)f2b(b.x); f[5] = (short)f2b(b.y);
            f[6] = (short)f2b(b.z); f[7] = (short)f2b(b.w);
            *(short8*)&wlds[(((wv * 2 + t2) * 8) + kb) * 512 + lane * 8] = f;
        }
    }
    // ---- fc tile (em weights) -> LDS, written by wave 7 ----
    if (wv == 7) {
#pragma unroll
        for (int kb = 0; kb < 8; ++kb) {
            short8 f;
            if (lo < KK) {
                const float4* p4 = (const float4*)(fcW + lo * (2 * HH) + dir * HH + kb * 32 + hi * 8);
                float4 a = p4[0], b = p4[1];
                f[0] = (short)f2b(a.x); f[1] = (short)f2b(a.y);
                f[2] = (short)f2b(a.z); f[3] = (short)f2b(a.w);
                f[4] = (short)f2b(b.x); f[5] = (short)f2b(b.y);
                f[6] = (short)f2b(b.z); f[7] = (short)f2b(b.w);
            } else {
                for (int j = 0; j < 8; ++j) f[j] = 0;
            }
            *(short8*)&fclds[kb * 512 + lane * 8] = f;
        }
    }
    __syncthreads();

    float cst[2][4] = {{0.f,0.f,0.f,0.f},{0.f,0.f,0.f,0.f}};
    const int bb0 = g * GB;
    // lane-constant pieces
    const int hwbase = ((((hi & 1) ? 0 : 0))); (void)hwbase;

    for (int s = 0; s <= TT; ++s) {
        floatx4 acc[8];
        if (s < TT) {
            // ---- acc init = gathered table row (bias + x@Wih folded, bf16) ----
            const int t = dir ? (TT - 1 - s) : s;
            const int cid = cidsT[t * BB + bb0 + lo];
            const unsigned short* trow = table + (size_t)cid * 1024 + wv * 32 + hi * 4;
#pragma unroll
            for (int tl = 0; tl < 8; ++tl) {
                const int q = tl >> 1, ct = tl & 1;
                uint2 v = *(const uint2*)(trow + q * HH + ct * 16);
                acc[tl][0] = b2f((unsigned short)(v.x & 0xffff));
                acc[tl][1] = b2f((unsigned short)(v.x >> 16));
                acc[tl][2] = b2f((unsigned short)(v.y & 0xffff));
                acc[tl][3] = b2f((unsigned short)(v.y >> 16));
            }
        }

        if (s > 0) {
            floatx4 eacc = {0.f, 0.f, 0.f, 0.f};
            const unsigned short* hb = &hfr[((s + 1) & 1) * 4096];
#pragma unroll
            for (int kb = 0; kb < 8; ++kb) {
                short8 hB = *(const short8*)&hb[kb * 512 + lane * 8];
                if (s < TT) {
#pragma unroll
                    for (int tl = 0; tl < 6; ++tl)
                        acc[tl] = __builtin_amdgcn_mfma_f32_16x16x32_bf16(wfrag[tl][kb], hB, acc[tl], 0, 0, 0);
#pragma unroll
                    for (int t2 = 0; t2 < 2; ++t2) {
                        short8 wA = *(const short8*)&wlds[(((wv * 2 + t2) * 8) + kb) * 512 + lane * 8];
                        acc[6 + t2] = __builtin_amdgcn_mfma_f32_16x16x32_bf16(wA, hB, acc[6 + t2], 0, 0, 0);
                    }
                }
                if (wv == 7) {
                    short8 fA = *(const short8*)&fclds[kb * 512 + lane * 8];
                    eacc = __builtin_amdgcn_mfma_f32_16x16x32_bf16(fA, hB, eacc, 0, 0, 0);
                }
            }
            if (wv == 7) {
                const int te = dir ? (TT - s) : (s - 1);
                float* eo = emOut + (size_t)(te * BB + bb0 + lo) * KK;
#pragma unroll
                for (int r = 0; r < 4; ++r) {
                    int tag = hi * 4 + r;
                    if (tag < KK) eo[tag] = eacc[r];
                }
            }
        }

        if (s < TT) {
            // ---- nonlinearity + c update + h pack/write (B-fragment-linear) ----
            unsigned short* hw = &hfr[(s & 1) * 4096];
#pragma unroll
            for (int ct = 0; ct < 2; ++ct) {
                unsigned pw0, pw1;
                unsigned short hb4[4];
#pragma unroll
                for (int r = 0; r < 4; ++r) {
                    float iv = acc[0 + ct][r];
                    float fv = acc[2 + ct][r];
                    float gv = acc[4 + ct][r];
                    float ov = acc[6 + ct][r];
                    float cn = fsig(fv) * cst[ct][r] + fsig(iv) * ftanh(gv);
                    cst[ct][r] = cn;
                    hb4[r] = f2b(fsig(ov) * ftanh(cn));
                }
                pw0 = (unsigned)hb4[0] | ((unsigned)hb4[1] << 16);
                pw1 = (unsigned)hb4[2] | ((unsigned)hb4[3] << 16);
                uint2 pv; pv.x = pw0; pv.y = pw1;
                const int idx = wv * 512 + ((ct * 2 + (hi >> 1)) * 16 + lo) * 8 + (hi & 1) * 4;
                *(uint2*)&hw[idx] = pv;
            }
        }
        __syncthreads();
    }
}

// ---------------- CRF partition (den): 16-lane group per batch row ----------------
__global__ void crf_den(const float* __restrict__ emF, const float* __restrict__ emB,
                        const float* __restrict__ fcb, const float* __restrict__ start_t,
                        const float* __restrict__ end_t, const float* __restrict__ trans,
                        float* __restrict__ den) {
    const int tid = threadIdx.x;
    const int j = tid & 15;
    const int grp = tid >> 4;
    const int b = blockIdx.x * 16 + grp;
    const bool valid = j < KK;

    __shared__ float expT[15][16];
    if (tid < 240) {
        int i = tid >> 4, jj = tid & 15;
        expT[i][jj] = (jj < KK) ? __expf(trans[i * KK + jj]) : 0.f;
    }
    __syncthreads();

    float fcbj = valid ? fcb[j] : 0.f;
    float alpha = -1e30f;
    if (valid) alpha = start_t[j] + emF[b * KK + j] + emB[b * KK + j] + fcbj;

    for (int t = 1; t < TT; ++t) {
        float m = alpha;
#pragma unroll
        for (int off = 8; off; off >>= 1)
            m = fmaxf(m, __shfl_xor(m, off, 16));
        float e = __expf(alpha - m);
        float S = 0.f;
#pragma unroll
        for (int i = 0; i < KK; ++i)
            S += __shfl(e, i, 16) * expT[i][j];
        float emv = 0.f;
        if (valid) emv = emF[(t * BB + b) * KK + j] + emB[(t * BB + b) * KK + j] + fcbj;
        float na = m + __logf(S) + emv;
        alpha = valid ? na : -1e30f;
    }
    float v = valid ? (alpha + end_t[j]) : -1e30f;
    float m = v;
#pragma unroll
    for (int off = 8; off; off >>= 1) m = fmaxf(m, __shfl_xor(m, off, 16));
    float e = __expf(v - m);
#pragma unroll
    for (int off = 8; off; off >>= 1) e += __shfl_xor(e, off, 16);
    if (j == 0) den[b] = m + __logf(e);
}

// ---------------- CRF numerator partials over t-chunks ----------------
__global__ void crf_num_part(const float* __restrict__ emF, const float* __restrict__ emB,
                             const float* __restrict__ fcb, const float* __restrict__ start_t,
                             const float* __restrict__ trans, const int* __restrict__ labelsT,
                             float* __restrict__ part) {
    const int b = threadIdx.x;
    const int q = blockIdx.x;
    const int t0 = q * 64;
    float p = 0.f;
    int lp = (t0 > 0) ? labelsT[(t0 - 1) * BB + b] : 0;
    for (int t = t0; t < t0 + 64; ++t) {
        int l = labelsT[t * BB + b];
        float em = emF[(t * BB + b) * KK + l] + emB[(t * BB + b) * KK + l] + fcb[l];
        if (t == 0) p += start_t[l] + em;
        else        p += trans[lp * KK + l] + em;
        lp = l;
    }
    part[q * BB + b] = p;
}

// ---------------- finalize ----------------
__global__ void finalize(const float* __restrict__ part, const float* __restrict__ den,
                         const float* __restrict__ end_t, const int* __restrict__ labelsT,
                         float* __restrict__ out) {
    const int b = threadIdx.x;
    float num = 0.f;
#pragma unroll
    for (int q = 0; q < 8; ++q) num += part[q * BB + b];
    num += end_t[labelsT[(TT - 1) * BB + b]];
    float v = num - den[b];
    __shared__ float red[256];
    red[b] = v;
    __syncthreads();
    for (int st = 128; st; st >>= 1) {
        if (b < st) red[b] += red[b + st];
        __syncthreads();
    }
    if (b == 0) out[0] = -(red[0] / (float)BB);
}

extern "C" void kernel_launch(void* const* d_in, const int* in_sizes, int n_in,
                              void* d_out, int out_size, void* d_ws, size_t ws_size,
                              hipStream_t stream) {
    const int* char_ids   = (const int*)d_in[0];
    const int* labels     = (const int*)d_in[1];
    const float* embed    = (const float*)d_in[3];
    const float* WihF     = (const float*)d_in[4];
    const float* WhhF     = (const float*)d_in[5];
    const float* bF       = (const float*)d_in[6];
    const float* WihB     = (const float*)d_in[7];
    const float* WhhB     = (const float*)d_in[8];
    const float* bB       = (const float*)d_in[9];
    const float* fcW      = (const float*)d_in[10];
    const float* fcb      = (const float*)d_in[11];
    const float* start_t  = (const float*)d_in[12];
    const float* end_t    = (const float*)d_in[13];
    const float* trans    = (const float*)d_in[14];

    char* w = (char*)d_ws;
    unsigned short* tableF = (unsigned short*)w;  w += 128 * 1024 * 2;
    unsigned short* tableB = (unsigned short*)w;  w += 128 * 1024 * 2;
    int* cidsT    = (int*)w;                      w += 512 * 256 * 4;
    int* labelsT  = (int*)w;                      w += 512 * 256 * 4;
    float* emF    = (float*)w;                    w += 512 * 256 * 15 * 4;
    float* emB    = (float*)w;                    w += 512 * 256 * 15 * 4;
    float* den    = (float*)w;                    w += 256 * 4;
    float* part   = (float*)w;                    w += 8 * 256 * 4;

    prep_transpose<<<1024, 256, 0, stream>>>(char_ids, labels, cidsT, labelsT);
    build_tables<<<1024, 256, 0, stream>>>(embed, WihF, bF, WihB, bB, tableF, tableB);

    bilstm<<<32, 512, 0, stream>>>(tableF, tableB, WhhF, WhhB, fcW, cidsT, emF, emB);

    crf_den<<<16, 256, 0, stream>>>(emF, emB, fcb, start_t, end_t, trans, den);
    crf_num_part<<<8, 256, 0, stream>>>(emF, emB, fcb, start_t, trans, labelsT, part);
    finalize<<<1, 256, 0, stream>>>(part, den, end_t, labelsT, (float*)d_out);
}

// Round 5
// 1633.960 us; speedup vs baseline: 2.0427x; 2.0427x over previous
//
#include <hip/hip_runtime.h>
#include <hip/hip_bf16.h>

#define BB 256   // batch
#define TT 512   // time
#define HH 256   // hidden
#define EE 128   // embed
#define KK 15    // tags
#define NGRP 16  // batch groups per direction
#define GB   16  // batch rows per group

typedef __attribute__((ext_vector_type(8))) short short8;
typedef __attribute__((ext_vector_type(4))) float floatx4;
typedef __attribute__((ext_vector_type(4))) unsigned int uint4v;

__device__ __forceinline__ float fsig(float x) { return 1.0f / (1.0f + __expf(-x)); }
__device__ __forceinline__ float ftanh(float x) {
    float e = __expf(2.0f * x);
    return 1.0f - 2.0f / (e + 1.0f);
}
__device__ __forceinline__ unsigned short f2b(float f) {
    __hip_bfloat16 h = __float2bfloat16(f);
    return *reinterpret_cast<unsigned short*>(&h);
}

// ---------------- fused prep: transpose ids/labels + build gate tables ----------------
__global__ void prep_fused(const int* __restrict__ cids, const int* __restrict__ labels,
                           int* __restrict__ cidsT, int* __restrict__ labelsT,
                           const float* __restrict__ embed,
                           const float* __restrict__ WihF, const float* __restrict__ bF,
                           const float* __restrict__ WihB, const float* __restrict__ bB,
                           float* __restrict__ tableF, float* __restrict__ tableB) {
    const int bidx = blockIdx.x;
    const int tid = threadIdx.x;
    if (bidx < 1024) {
        int idx = bidx * 256 + tid;          // 0..262143
        int which = idx >> 17;
        int r = idx & 131071;
        int b = r >> 9, t = r & 511;
        if (which == 0) cidsT[t * BB + b] = cids[b * TT + t];
        else            labelsT[t * BB + b] = labels[b * TT + t];
    } else {
        int idx = (bidx - 1024) * 256 + tid; // 0..262143
        int d = idx >> 17;
        int r = idx & 131071;
        int v = r >> 10, j = r & 1023;
        const float* Wih = d ? WihB : WihF;
        const float* bias = d ? bB : bF;
        float s = bias[j];
        const float* em = embed + v * EE;
        const float* wr = Wih + j * EE;
#pragma unroll 8
        for (int e = 0; e < EE; ++e) s += em[e] * wr[e];
        (d ? tableB : tableF)[v * 1024 + j] = s;
    }
}

// ---------------- BiLSTM: tag-in-data exchange, no atomics, no fences ----------------
// 128 blocks x 256 threads: bid = jb*32 + gi; gi = dir*16 + g; jb in 0..3 owns
// h-cols [jb*64, jb*64+64). Wave wv owns cols jb*64 + wv*16 + (lane&15), 4 gates.
// hws: u32 words [(dir*16+g)][col(256)][b(16)], word = (tag<<16) | bf16(h).
// Producer at step s writes tag s+1; consumer at step s polls for tag s.
__global__ void __launch_bounds__(256, 1)
bilstm(const float* __restrict__ tableF, const float* __restrict__ tableB,
       const float* __restrict__ WhhF, const float* __restrict__ WhhB,
       const float* __restrict__ fcW,
       const int* __restrict__ cidsT,
       unsigned* __restrict__ hws,
       float* __restrict__ emF, float* __restrict__ emB) {
    const int bid = blockIdx.x;
    const int gi  = bid & 31;
    const int jb  = bid >> 5;          // 0..3
    const int dir = gi >> 4;
    const int g   = gi & 15;
    const int tid = threadIdx.x;
    const int lane = tid & 63;
    const int wv  = tid >> 6;          // 0..3
    const int lo  = lane & 15;
    const int hi  = lane >> 4;         // 0..3

    const float* table = dir ? tableB : tableF;
    const float* Whh   = dir ? WhhB : WhhF;
    float* emOut       = dir ? emB : emF;

    __shared__ __align__(16) unsigned short h_lds[2][16][264];  // [buf][b][col], 16.9 KiB

    const int colg = jb * 64 + wv * 16 + lo;      // this lane's h-col (0..255)
    const int bb0 = g * GB;
    unsigned* slab = hws + gi * 4096;             // 16 KiB of u32 per (dir,g)

    // ---- preload Whh B-fragments: B[k][col] = Whh[q*HH+colg][k] ----
    short8 wfrag[4][8];
#pragma unroll
    for (int q = 0; q < 4; ++q) {
        const float* wrow = Whh + (size_t)(q * HH + colg) * HH;
#pragma unroll
        for (int kb = 0; kb < 8; ++kb) {
            const float4* p4 = (const float4*)(wrow + kb * 32 + hi * 8);
            float4 a = p4[0], b = p4[1];
            short8 f;
            f[0] = (short)f2b(a.x); f[1] = (short)f2b(a.y);
            f[2] = (short)f2b(a.z); f[3] = (short)f2b(a.w);
            f[4] = (short)f2b(b.x); f[5] = (short)f2b(b.y);
            f[6] = (short)f2b(b.z); f[7] = (short)f2b(b.w);
            wfrag[q][kb] = f;
        }
    }
    // ---- em B-fragments (fcW), used by block jb==0 wave 0 only ----
    short8 efrag[8];
    if (jb == 0 && wv == 0) {
#pragma unroll
        for (int kb = 0; kb < 8; ++kb) {
            short8 f;
            if (lo < KK) {
                const float4* p4 = (const float4*)(fcW + lo * (2 * HH) + dir * HH + kb * 32 + hi * 8);
                float4 a = p4[0], b = p4[1];
                f[0] = (short)f2b(a.x); f[1] = (short)f2b(a.y);
                f[2] = (short)f2b(a.z); f[3] = (short)f2b(a.w);
                f[4] = (short)f2b(b.x); f[5] = (short)f2b(b.y);
                f[6] = (short)f2b(b.z); f[7] = (short)f2b(b.w);
            } else {
                for (int j = 0; j < 8; ++j) f[j] = 0;
            }
            efrag[kb] = f;
        }
    }

    float cst[4] = {0.f, 0.f, 0.f, 0.f};

    for (int s = 0; s <= TT; ++s) {
        // ---- (1) table gather issued first: hides L2 latency under the poll ----
        float tv[16];
        if (s < TT) {
            const int t = dir ? (TT - 1 - s) : s;
            int cid[4];
#pragma unroll
            for (int r = 0; r < 4; ++r) cid[r] = cidsT[t * BB + bb0 + hi * 4 + r];
#pragma unroll
            for (int q = 0; q < 4; ++q)
#pragma unroll
                for (int r = 0; r < 4; ++r)
                    tv[q * 4 + r] = table[(size_t)cid[r] * 1024 + q * HH + colg];
        }

        // ---- (2) poll h_{s-1}: tags carried inside the data words ----
        if (s > 0) {
            const unsigned* src = slab + tid * 16;
            const unsigned want = ((unsigned)s) << 16;
            uint4v w0, w1, w2, w3;
            for (;;) {
                asm volatile(
                    "global_load_dwordx4 %0, %4, off sc0 sc1\n\t"
                    "global_load_dwordx4 %1, %5, off sc0 sc1\n\t"
                    "global_load_dwordx4 %2, %6, off sc0 sc1\n\t"
                    "global_load_dwordx4 %3, %7, off sc0 sc1\n\t"
                    "s_waitcnt vmcnt(0)"
                    : "=&v"(w0), "=&v"(w1), "=&v"(w2), "=&v"(w3)
                    : "v"(src), "v"(src + 4), "v"(src + 8), "v"(src + 12)
                    : "memory");
                bool ok = ((w0[0] & 0xffff0000u) == want) & ((w0[1] & 0xffff0000u) == want)
                        & ((w0[2] & 0xffff0000u) == want) & ((w0[3] & 0xffff0000u) == want)
                        & ((w1[0] & 0xffff0000u) == want) & ((w1[1] & 0xffff0000u) == want)
                        & ((w1[2] & 0xffff0000u) == want) & ((w1[3] & 0xffff0000u) == want)
                        & ((w2[0] & 0xffff0000u) == want) & ((w2[1] & 0xffff0000u) == want)
                        & ((w2[2] & 0xffff0000u) == want) & ((w2[3] & 0xffff0000u) == want)
                        & ((w3[0] & 0xffff0000u) == want) & ((w3[1] & 0xffff0000u) == want)
                        & ((w3[2] & 0xffff0000u) == want) & ((w3[3] & 0xffff0000u) == want);
                if (ok) break;
            }
            unsigned short (*hl)[264] = h_lds[(s + 1) & 1];
            hl[ 0][tid] = (unsigned short)w0[0]; hl[ 1][tid] = (unsigned short)w0[1];
            hl[ 2][tid] = (unsigned short)w0[2]; hl[ 3][tid] = (unsigned short)w0[3];
            hl[ 4][tid] = (unsigned short)w1[0]; hl[ 5][tid] = (unsigned short)w1[1];
            hl[ 6][tid] = (unsigned short)w1[2]; hl[ 7][tid] = (unsigned short)w1[3];
            hl[ 8][tid] = (unsigned short)w2[0]; hl[ 9][tid] = (unsigned short)w2[1];
            hl[10][tid] = (unsigned short)w2[2]; hl[11][tid] = (unsigned short)w2[3];
            hl[12][tid] = (unsigned short)w3[0]; hl[13][tid] = (unsigned short)w3[1];
            hl[14][tid] = (unsigned short)w3[2]; hl[15][tid] = (unsigned short)w3[3];
        }
        __syncthreads();

        // ---- (3) gates MFMA + nonlinearity + tagged h store (critical path) ----
        if (s < TT) {
            floatx4 acc[4];
#pragma unroll
            for (int q = 0; q < 4; ++q) {
                acc[q][0] = tv[q * 4 + 0]; acc[q][1] = tv[q * 4 + 1];
                acc[q][2] = tv[q * 4 + 2]; acc[q][3] = tv[q * 4 + 3];
            }
            if (s > 0) {
                const unsigned short (*hl)[264] = h_lds[(s + 1) & 1];
#pragma unroll
                for (int kb = 0; kb < 8; ++kb) {
                    short8 a = *(const short8*)&hl[lo][kb * 32 + hi * 8];
#pragma unroll
                    for (int q = 0; q < 4; ++q)
                        acc[q] = __builtin_amdgcn_mfma_f32_16x16x32_bf16(a, wfrag[q][kb], acc[q], 0, 0, 0);
                }
            }
            unsigned hb[4];
#pragma unroll
            for (int r = 0; r < 4; ++r) {
                float iv = acc[0][r], fv = acc[1][r], gv = acc[2][r], ov = acc[3][r];
                float cn = fsig(fv) * cst[r] + fsig(iv) * ftanh(gv);
                cst[r] = cn;
                hb[r] = (unsigned)f2b(fsig(ov) * ftanh(cn));
            }
            const unsigned tagw = ((unsigned)(s + 1)) << 16;
            uint4v pv;
            pv[0] = tagw | hb[0]; pv[1] = tagw | hb[1];
            pv[2] = tagw | hb[2]; pv[3] = tagw | hb[3];
            unsigned* dst = slab + colg * 16 + hi * 4;
            asm volatile("global_store_dwordx4 %0, %1, off sc0 sc1"
                         :: "v"(dst), "v"(pv) : "memory");
        }

        // ---- (4) em for h_{s-1} — after the h store, off the critical path ----
        if (s > 0 && jb == 0 && wv == 0) {
            const unsigned short (*hl)[264] = h_lds[(s + 1) & 1];
            floatx4 eacc = {0.f, 0.f, 0.f, 0.f};
#pragma unroll
            for (int kb = 0; kb < 8; ++kb) {
                short8 a = *(const short8*)&hl[lo][kb * 32 + hi * 8];
                eacc = __builtin_amdgcn_mfma_f32_16x16x32_bf16(a, efrag[kb], eacc, 0, 0, 0);
            }
            if (lo < KK) {
                const int te = dir ? (TT - s) : (s - 1);
                float* eo = emOut + (size_t)(te * BB + bb0) * KK + lo;
#pragma unroll
                for (int r = 0; r < 4; ++r)
                    eo[(hi * 4 + r) * KK] = eacc[r];
            }
        }
    }
}

// ---------------- CRF partition (den): 16-lane group per batch row ----------------
__global__ void crf_den(const float* __restrict__ emF, const float* __restrict__ emB,
                        const float* __restrict__ fcb, const float* __restrict__ start_t,
                        const float* __restrict__ end_t, const float* __restrict__ trans,
                        float* __restrict__ den) {
    const int tid = threadIdx.x;
    const int j = tid & 15;
    const int grp = tid >> 4;
    const int b = blockIdx.x * 16 + grp;
    const bool valid = j < KK;

    __shared__ float expT[15][16];
    if (tid < 240) {
        int i = tid >> 4, jj = tid & 15;
        expT[i][jj] = (jj < KK) ? __expf(trans[i * KK + jj]) : 0.f;
    }
    __syncthreads();

    float fcbj = valid ? fcb[j] : 0.f;
    float alpha = -1e30f;
    if (valid) alpha = start_t[j] + emF[b * KK + j] + emB[b * KK + j] + fcbj;

    for (int t = 1; t < TT; ++t) {
        float m = alpha;
#pragma unroll
        for (int off = 8; off; off >>= 1)
            m = fmaxf(m, __shfl_xor(m, off, 16));
        float e = __expf(alpha - m);
        float S = 0.f;
#pragma unroll
        for (int i = 0; i < KK; ++i)
            S += __shfl(e, i, 16) * expT[i][j];
        float emv = 0.f;
        if (valid) emv = emF[(t * BB + b) * KK + j] + emB[(t * BB + b) * KK + j] + fcbj;
        float na = m + __logf(S) + emv;
        alpha = valid ? na : -1e30f;
    }
    float v = valid ? (alpha + end_t[j]) : -1e30f;
    float m = v;
#pragma unroll
    for (int off = 8; off; off >>= 1) m = fmaxf(m, __shfl_xor(m, off, 16));
    float e = __expf(v - m);
#pragma unroll
    for (int off = 8; off; off >>= 1) e += __shfl_xor(e, off, 16);
    if (j == 0) den[b] = m + __logf(e);
}

// ---------------- CRF numerator partials over t-chunks ----------------
__global__ void crf_num_part(const float* __restrict__ emF, const float* __restrict__ emB,
                             const float* __restrict__ fcb, const float* __restrict__ start_t,
                             const float* __restrict__ trans, const int* __restrict__ labelsT,
                             float* __restrict__ part) {
    const int b = threadIdx.x;
    const int q = blockIdx.x;
    const int t0 = q * 64;
    float p = 0.f;
    int lp = (t0 > 0) ? labelsT[(t0 - 1) * BB + b] : 0;
    for (int t = t0; t < t0 + 64; ++t) {
        int l = labelsT[t * BB + b];
        float em = emF[(t * BB + b) * KK + l] + emB[(t * BB + b) * KK + l] + fcb[l];
        if (t == 0) p += start_t[l] + em;
        else        p += trans[lp * KK + l] + em;
        lp = l;
    }
    part[q * BB + b] = p;
}

// ---------------- finalize ----------------
__global__ void finalize(const float* __restrict__ part, const float* __restrict__ den,
                         const float* __restrict__ end_t, const int* __restrict__ labelsT,
                         float* __restrict__ out) {
    const int b = threadIdx.x;
    float num = 0.f;
#pragma unroll
    for (int q = 0; q < 8; ++q) num += part[q * BB + b];
    num += end_t[labelsT[(TT - 1) * BB + b]];
    float v = num - den[b];
    __shared__ float red[256];
    red[b] = v;
    __syncthreads();
    for (int st = 128; st; st >>= 1) {
        if (b < st) red[b] += red[b + st];
        __syncthreads();
    }
    if (b == 0) out[0] = -(red[0] / (float)BB);
}

extern "C" void kernel_launch(void* const* d_in, const int* in_sizes, int n_in,
                              void* d_out, int out_size, void* d_ws, size_t ws_size,
                              hipStream_t stream) {
    const int* char_ids   = (const int*)d_in[0];
    const int* labels     = (const int*)d_in[1];
    const float* embed    = (const float*)d_in[3];
    const float* WihF     = (const float*)d_in[4];
    const float* WhhF     = (const float*)d_in[5];
    const float* bF       = (const float*)d_in[6];
    const float* WihB     = (const float*)d_in[7];
    const float* WhhB     = (const float*)d_in[8];
    const float* bB       = (const float*)d_in[9];
    const float* fcW      = (const float*)d_in[10];
    const float* fcb      = (const float*)d_in[11];
    const float* start_t  = (const float*)d_in[12];
    const float* end_t    = (const float*)d_in[13];
    const float* trans    = (const float*)d_in[14];

    char* w = (char*)d_ws;
    float* tableF = (float*)w;          w += 128 * 1024 * 4;
    float* tableB = (float*)w;          w += 128 * 1024 * 4;
    int* cidsT    = (int*)w;            w += 512 * 256 * 4;
    int* labelsT  = (int*)w;            w += 512 * 256 * 4;
    unsigned* hws = (unsigned*)w;       w += 2 * NGRP * HH * GB * 4;   // 512 KiB
    float* emF    = (float*)w;          w += 512 * 256 * 15 * 4;
    float* emB    = (float*)w;          w += 512 * 256 * 15 * 4;
    float* den    = (float*)w;          w += 256 * 4;
    float* part   = (float*)w;          w += 8 * 256 * 4;

    hipMemsetAsync(hws, 0, 2 * NGRP * HH * GB * 4, stream);
    prep_fused<<<2048, 256, 0, stream>>>(char_ids, labels, cidsT, labelsT,
                                         embed, WihF, bF, WihB, bB, tableF, tableB);

    void* args[] = { (void*)&tableF, (void*)&tableB, (void*)&WhhF, (void*)&WhhB,
                     (void*)&fcW, (void*)&cidsT, (void*)&hws, (void*)&emF, (void*)&emB };
    hipLaunchCooperativeKernel((void*)bilstm, dim3(128), dim3(256), args, 0, stream);

    crf_den<<<16, 256, 0, stream>>>(emF, emB, fcb, start_t, end_t, trans, den);
    crf_num_part<<<8, 256, 0, stream>>>(emF, emB, fcb, start_t, trans, labelsT, part);
    finalize<<<1, 256, 0, stream>>>(part, den, end_t, labelsT, (float*)d_out);
}